// Round 11
// baseline (284.663 us; speedup 1.0000x reference)
//
#include <hip/hip_runtime.h>
#include <hip/hip_fp16.h>
#include <hip/hip_bf16.h>

constexpr int BB  = 8;
constexpr int NN  = 4096;
constexpr int CC  = 256;
constexpr int CKK = 32;

typedef __attribute__((ext_vector_type(8))) short    short8;  // 8 x bf16 bits
typedef __attribute__((ext_vector_type(8))) _Float16 half8;
typedef __attribute__((ext_vector_type(4))) _Float16 half4;
typedef __attribute__((ext_vector_type(4))) float    f32x4;

__device__ __forceinline__ unsigned short bf16_bits(float v) {
    __hip_bfloat16 h = __float2bfloat16(v);
    return *reinterpret_cast<unsigned short*>(&h);
}
__device__ __forceinline__ float bf16_val(unsigned short u) {
    __hip_bfloat16 h = *reinterpret_cast<__hip_bfloat16*>(&u);
    return __bfloat162float(h);
}

// ---------------------------------------------------------------------------
// K0: transpose + bf16 hi/lo split of all weights into WT[576][256]:
// rows 0..255 = Wh cols, 256..287 = Wf, 288..319 = Wg, 320..575 = Wo.
// ---------------------------------------------------------------------------
__global__ __launch_bounds__(256) void prep_kernel(
    const float* __restrict__ Wf, const float* __restrict__ Wg,
    const float* __restrict__ Wh, const float* __restrict__ Wo,
    unsigned short* __restrict__ WThi, unsigned short* __restrict__ WTlo)
{
    const int n = blockIdx.x;
    const int k = threadIdx.x;
    float v;
    if      (n < 256) v = Wh[k * 256 + n];
    else if (n < 288) v = Wf[k * 32 + (n - 256)];
    else if (n < 320) v = Wg[k * 32 + (n - 288)];
    else              v = Wo[k * 256 + (n - 320)];
    const unsigned short hi = bf16_bits(v);
    WThi[n * 256 + k] = hi;
    WTlo[n * 256 + k] = bf16_bits(v - bf16_val(hi));
}

// ---------------------------------------------------------------------------
// K1: projections. r10's LDS-staged A kept. NEW: coalesced hhT stores.
// Old hhT store: c = ln -> 16 lanes write 8 B at 8 KB stride = 16 scattered
// 32 B fragments per instruction; hhT = 16.8 MB as ~525K partial-line
// transactions. (All four prior fgh theories attacked the LOAD side and
// were ~neutral -- the store pattern survived every round.)
// New: after the k-loop XT is dead -> per-wave [16][68] fp16 staging tile
// aliased over XT[0]. Per hhT nt-tile: stage bias-added half4s transposed
// (<=4-way write conflict on 16 cheap ds_writes), then 2 coalesced b128
// stores: 8 channel-rows x 128 B = 1 KB per instruction. fp16 bits pass
// through LDS unchanged -> bitwise-identical hhT. f/g keep old path (4 MB).
// ---------------------------------------------------------------------------
__global__ __launch_bounds__(256) void fgh_kernel(
    const float* __restrict__ x,
    const unsigned short* __restrict__ WThi, const unsigned short* __restrict__ WTlo,
    const float* __restrict__ bf, const float* __restrict__ bg,
    const float* __restrict__ bh,
    _Float16* __restrict__ fbuf, _Float16* __restrict__ gbuf,
    _Float16* __restrict__ hhT)
{
    __shared__ __align__(16) float XT[2][64 * 36];   // 2 x 9.2 KB dbuf

    const int tid = threadIdx.x, w = tid >> 6, lane = tid & 63;
    const int ln = lane & 15, lq = lane >> 4;
    const int b  = blockIdx.x & 7;               // batch == XCD
    const int q0 = (blockIdx.x >> 3) * 64;
    const size_t px0 = (size_t)b * NN + q0;      // block's 64 pixels
    const int n0 = w * 80;                       // wave's 80 output columns

    // staging role: thread t covers row p = t/4, k-quarter jq = t%4
    const int p  = tid >> 2;
    const int jq = tid & 3;
    const float* xrow = &x[(px0 + p) * CC + jq * 8];

    f32x4 acc[4][5];   // [mt][nt]
    #pragma unroll
    for (int i = 0; i < 4; ++i)
        #pragma unroll
        for (int j = 0; j < 5; ++j) acc[i][j] = {0.f, 0.f, 0.f, 0.f};

    short8 Ahi[4], Alo[4];
    float4 ra0 = *(const float4*)&xrow[0];
    float4 ra1 = *(const float4*)&xrow[4];

    int cur = 0;
    #pragma unroll 1
    for (int kc = 0; kc < 8; ++kc) {
        const int k0 = kc * 32;
        // stage this tile from regs to LDS
        float* dst = &XT[cur][p * 36 + jq * 8];
        *(float4*)&dst[0] = ra0;
        *(float4*)&dst[4] = ra1;
        __syncthreads();
        // prefetch next tile (in flight across the whole compute phase)
        if (kc < 7) {
            ra0 = *(const float4*)&xrow[(kc + 1) * 32];
            ra1 = *(const float4*)&xrow[(kc + 1) * 32 + 4];
        }
        // A-frags from LDS + identical conversion
        #pragma unroll
        for (int mt = 0; mt < 4; ++mt) {
            float av[8];
            const float* sp = &XT[cur][(mt * 16 + ln) * 36 + lq * 8];
            *(float4*)&av[0] = *(const float4*)&sp[0];
            *(float4*)&av[4] = *(const float4*)&sp[4];
            #pragma unroll
            for (int j = 0; j < 8; ++j) {
                const unsigned short h = bf16_bits(av[j]);
                Ahi[mt][j] = (short)h;
                Alo[mt][j] = (short)bf16_bits(av[j] - bf16_val(h));
            }
        }
        #pragma unroll
        for (int nt = 0; nt < 5; ++nt) {
            const size_t boff = (size_t)(n0 + nt * 16 + ln) * 256 + k0 + lq * 8;
            const short8 Bhi = *(const short8*)&WThi[boff];
            const short8 Blo = *(const short8*)&WTlo[boff];
            #pragma unroll
            for (int mt = 0; mt < 4; ++mt) {
                acc[mt][nt] = __builtin_amdgcn_mfma_f32_16x16x32_bf16(Ahi[mt], Bhi, acc[mt][nt], 0, 0, 0);
                acc[mt][nt] = __builtin_amdgcn_mfma_f32_16x16x32_bf16(Ahi[mt], Blo, acc[mt][nt], 0, 0, 0);
                acc[mt][nt] = __builtin_amdgcn_mfma_f32_16x16x32_bf16(Alo[mt], Bhi, acc[mt][nt], 0, 0, 0);
            }
        }
        cur ^= 1;
    }

    // ---- stores ----
    // per-wave fp16 staging tile [16][68], aliased over the now-dead XT[0]
    // (all waves' final XT reads completed before their own epilogue; each
    // wave touches only its private 2176 B region).
    _Float16* st = (_Float16*)&XT[0][0] + w * 1088;
    const int rr = lane >> 3, k8 = lane & 7;

    #pragma unroll
    for (int nt = 0; nt < 5; ++nt) {
        const int cbase = n0 + nt * 16;
        const int c = cbase + ln;
        if (cbase < 256) {
            // hhT tile: stage transposed in LDS, then 2 coalesced 1KB stores
            const float bias = bh[c];
            #pragma unroll
            for (int mt = 0; mt < 4; ++mt) {
                half4 hv;
                #pragma unroll
                for (int r = 0; r < 4; ++r) hv[r] = (_Float16)(acc[mt][nt][r] + bias);
                *(half4*)&st[ln * 68 + mt * 16 + lq * 4] = hv;
            }
            #pragma unroll
            for (int i = 0; i < 2; ++i) {
                const half8 row = *(const half8*)&st[(i * 8 + rr) * 68 + k8 * 8];
                *(half8*)&hhT[((size_t)(b * CC + cbase + i * 8 + rr)) * NN + q0 + k8 * 8] = row;
            }
        } else {
            const bool isf = (c < 288);
            const int d = isf ? (c - 256) : (c - 288);
            const float bias = isf ? bf[d] : bg[d];
            _Float16* dst2 = isf ? fbuf : gbuf;
            #pragma unroll
            for (int mt = 0; mt < 4; ++mt)
                #pragma unroll
                for (int r = 0; r < 4; ++r)
                    dst2[(px0 + mt * 16 + lq * 4 + r) * CKK + d] =
                        (_Float16)(acc[mt][nt][r] + bias);
        }
    }
}

// ---------------------------------------------------------------------------
// K2: MFMA flash attention + FUSED output GEMM (round-8/9 state, unchanged).
// Block = 64 q x 256 c; 4 waves; grid 512. Main loop: phaseA (S^T -> exp ->
// P LDS dbuf) | barrier | post-barrier Bh prefetch | phaseB (PV, register-
// dbuf Bh). Epilogue: normalize O -> LDS OF[64][268] (aliases dead P) ->
// out_kernel inner loop per wave -> gamma/bias/x epilogue. Bitwise-identical.
// ---------------------------------------------------------------------------
__global__ __launch_bounds__(256, 2) void attn_kernel(
    const _Float16* __restrict__ fbuf, const _Float16* __restrict__ gbuf,
    const _Float16* __restrict__ hhT,
    const unsigned short* __restrict__ WThi, const unsigned short* __restrict__ WTlo,
    const float* __restrict__ bo, const float* __restrict__ gamma,
    const float* __restrict__ x, float* __restrict__ out)
{
    // OF (epilogue o-staging, f32 [64][268]) aliases P (main-loop dbuf).
    __shared__ __align__(16) float OF[64 * 268];          // 68.6 KB
    _Float16* P0 = (_Float16*)OF;                          // [64*72] fp16
    _Float16* P1 = P0 + 64 * 72;
    __shared__ float mxbuf[4][64];
    __shared__ float rsbuf[4][64];

    const int tid = threadIdx.x, w = tid >> 6, lane = tid & 63;
    const int ln = lane & 15, lq = lane >> 4;
    const int b  = blockIdx.x & 7;               // batch == XCD
    const int q0 = (blockIdx.x >> 3) * 64;
    const int cb = w * 64;                       // this wave's channel base

    const f32x4 zero = {0.f, 0.f, 0.f, 0.f};
    constexpr float LOG2E = 1.4426950408889634f;

    // persistent g B-frags: B[k=d][n=q]
    half8 Bg[4];
    #pragma unroll
    for (int qt = 0; qt < 4; ++qt)
        Bg[qt] = *(const half8*)&gbuf[(size_t)(b * NN + q0 + qt * 16 + ln) * CKK + lq * 8];

    // base pointers (advance by constants inside loops)
    const _Float16* fb = &fbuf[(size_t)(b * NN + w * 16 + ln) * CKK + lq * 8];
    const _Float16* hb = &hhT[((size_t)(b * CC + cb + ln)) * NN + lq * 8];

    // ---- pass 1: rowmax (wave w covers keys j0 + w*16 + 0..15), pipelined ----
    float mx[4];
    #pragma unroll
    for (int qt = 0; qt < 4; ++qt) mx[qt] = -1e30f;
    half8 Afc = *(const half8*)fb;
    #pragma unroll 1
    for (int j0 = 0; j0 < NN; j0 += 64) {
        const int jn = (j0 + 64 < NN) ? j0 + 64 : j0;
        const half8 Afn = *(const half8*)&fb[(size_t)jn * CKK];
        #pragma unroll
        for (int qt = 0; qt < 4; ++qt) {
            const f32x4 s = __builtin_amdgcn_mfma_f32_16x16x32_f16(Afc, Bg[qt], zero, 0, 0, 0);
            mx[qt] = fmaxf(mx[qt], fmaxf(fmaxf(s[0], s[1]), fmaxf(s[2], s[3])));
        }
        Afc = Afn;
    }
    #pragma unroll
    for (int qt = 0; qt < 4; ++qt) {
        mx[qt] = fmaxf(mx[qt], __shfl_xor(mx[qt], 16));
        mx[qt] = fmaxf(mx[qt], __shfl_xor(mx[qt], 32));
    }
    if (lane < 16) {
        #pragma unroll
        for (int qt = 0; qt < 4; ++qt) mxbuf[w][qt * 16 + ln] = mx[qt];
    }
    __syncthreads();
    float mk[4];   // per-lane: q = qt*16 + ln
    #pragma unroll
    for (int qt = 0; qt < 4; ++qt)
        mk[qt] = LOG2E * fmaxf(fmaxf(mxbuf[0][qt * 16 + ln], mxbuf[1][qt * 16 + ln]),
                               fmaxf(mxbuf[2][qt * 16 + ln], mxbuf[3][qt * 16 + ln]));

    // ---- main loop ----
    f32x4 O[4][4];     // [qt][ct]
    #pragma unroll
    for (int qt = 0; qt < 4; ++qt)
        #pragma unroll
        for (int ct = 0; ct < 4; ++ct) O[qt][ct] = zero;
    float psum[4] = {0.f, 0.f, 0.f, 0.f};

    // phase A: S^T -> exp -> P (LDS); identical MFMA to pass 1
    auto phaseA = [&](const half8& Af, _Float16* Pb) {
        #pragma unroll
        for (int qt = 0; qt < 4; ++qt) {
            const f32x4 s = __builtin_amdgcn_mfma_f32_16x16x32_f16(Af, Bg[qt], zero, 0, 0, 0);
            half4 ph;
            float ps = 0.f;
            #pragma unroll
            for (int r = 0; r < 4; ++r) {
                const float p = exp2f(fmaf(s[r], LOG2E, -mk[qt]));
                ps += p;
                ph[r] = (_Float16)p;
            }
            psum[qt] += ps;
            // P[q = qt*16+ln][key = w*16 + lq*4 + r]  (A-layout, pad 72)
            *(half4*)&Pb[(qt * 16 + ln) * 72 + w * 16 + lq * 4] = ph;
        }
    };

    // issue 8 global b128 loads of hhT B-frags for key block j0
    auto loadBh = [&](half8 (&Bh)[4][2], int j0) {
        #pragma unroll
        for (int ct = 0; ct < 4; ++ct)
            #pragma unroll
            for (int kh = 0; kh < 2; ++kh)
                Bh[ct][kh] = *(const half8*)&hb[(size_t)ct * 16 * NN + j0 + kh * 32];
    };

    // phase B: PV for this wave's 64 channels, K=64 via 2 K32 halves
    auto phaseB = [&](const half8 (&Bh)[4][2], const _Float16* Pb) {
        __builtin_amdgcn_s_setprio(1);
        #pragma unroll
        for (int qt = 0; qt < 4; ++qt) {
            const half8 Ap0 = *(const half8*)&Pb[(qt * 16 + ln) * 72 + lq * 8];
            const half8 Ap1 = *(const half8*)&Pb[(qt * 16 + ln) * 72 + 32 + lq * 8];
            #pragma unroll
            for (int ct = 0; ct < 4; ++ct) {
                O[qt][ct] = __builtin_amdgcn_mfma_f32_16x16x32_f16(Ap0, Bh[ct][0], O[qt][ct], 0, 0, 0);
                O[qt][ct] = __builtin_amdgcn_mfma_f32_16x16x32_f16(Ap1, Bh[ct][1], O[qt][ct], 0, 0, 0);
            }
        }
        __builtin_amdgcn_s_setprio(0);
    };

    // prologue: current-iter buffers
    half8 Bh0[4][2], Bh1[4][2];
    half8 Af0, Af1;
    loadBh(Bh0, 0);
    Af0 = *(const half8*)fb;

    #pragma unroll 1
    for (int j0 = 0; j0 < NN; j0 += 128) {
        // --- even 64-key block: uses Bh0/Af0, prefetches Bh1/Af1 ---
        phaseA(Af0, P0);
        __syncthreads();                         // drains Bh0 (issued 1 iter ago)
        loadBh(Bh1, j0 + 64);                    // post-barrier issue: lands during
        Af1 = *(const half8*)&fb[(size_t)(j0 + 64) * CKK];  // phaseB + next phaseA
        phaseB(Bh0, P0);
        // --- odd 64-key block: uses Bh1/Af1, prefetches Bh0/Af0 ---
        phaseA(Af1, P1);
        __syncthreads();
        if (j0 + 128 < NN) {
            loadBh(Bh0, j0 + 128);
            Af0 = *(const half8*)&fb[(size_t)(j0 + 128) * CKK];
        }
        phaseB(Bh1, P1);
    }

    // ---- rowsum merge across waves ----
    #pragma unroll
    for (int qt = 0; qt < 4; ++qt) {
        psum[qt] += __shfl_xor(psum[qt], 16);
        psum[qt] += __shfl_xor(psum[qt], 32);
    }
    if (lane < 16) {
        #pragma unroll
        for (int qt = 0; qt < 4; ++qt) rsbuf[w][qt * 16 + ln] = psum[qt];
    }
    __syncthreads();   // also: all phaseB P-reads done -> P (alias OF) is dead

    // ---- stage normalized o into LDS OF[64][268] (f32, same values the
    //      old obuf held) ----
    #pragma unroll
    for (int qt = 0; qt < 4; ++qt)
        #pragma unroll
        for (int r = 0; r < 4; ++r) {
            const int q = qt * 16 + lq * 4 + r;
            const float rinv = 1.0f / (rsbuf[0][q] + rsbuf[1][q] + rsbuf[2][q] + rsbuf[3][q]);
            #pragma unroll
            for (int ct = 0; ct < 4; ++ct)
                OF[q * 268 + cb + ct * 16 + ln] = O[qt][ct][r] * rinv;
        }
    __syncthreads();

    // ---- fused out-GEMM: out[64 q][256 c] = gamma*(o @ Wo + bo) + x.
    //      Wave w handles out-channels n0 = w*64 .. +63; identical inner
    //      loop to the old out_kernel (bitwise-same accumulation). ----
    {
        const int n0 = w * 64;
        f32x4 acc[4][4];
        #pragma unroll
        for (int i = 0; i < 4; ++i)
            #pragma unroll
            for (int j = 0; j < 4; ++j) acc[i][j] = {0.f, 0.f, 0.f, 0.f};

        short8 Ahi[4], Alo[4];
        #pragma unroll 1
        for (int kc = 0; kc < 8; ++kc) {
            const int k0 = kc * 32;
            #pragma unroll
            for (int mt = 0; mt < 4; ++mt) {
                float av[8];
                *(f32x4*)&av[0] = *(const f32x4*)&OF[(mt * 16 + ln) * 268 + k0 + lq * 8];
                *(f32x4*)&av[4] = *(const f32x4*)&OF[(mt * 16 + ln) * 268 + k0 + lq * 8 + 4];
                #pragma unroll
                for (int j = 0; j < 8; ++j) {
                    const unsigned short h = bf16_bits(av[j]);
                    Ahi[mt][j] = (short)h;
                    Alo[mt][j] = (short)bf16_bits(av[j] - bf16_val(h));
                }
            }
            #pragma unroll
            for (int nt = 0; nt < 4; ++nt) {
                const size_t boff = (size_t)(320 + n0 + nt * 16 + ln) * 256 + k0 + lq * 8;
                const short8 Bhi = *(const short8*)&WThi[boff];
                const short8 Blo = *(const short8*)&WTlo[boff];
                #pragma unroll
                for (int mt = 0; mt < 4; ++mt) {
                    acc[mt][nt] = __builtin_amdgcn_mfma_f32_16x16x32_bf16(Ahi[mt], Bhi, acc[mt][nt], 0, 0, 0);
                    acc[mt][nt] = __builtin_amdgcn_mfma_f32_16x16x32_bf16(Ahi[mt], Blo, acc[mt][nt], 0, 0, 0);
                    acc[mt][nt] = __builtin_amdgcn_mfma_f32_16x16x32_bf16(Alo[mt], Bhi, acc[mt][nt], 0, 0, 0);
                }
            }
        }

        const float gm = gamma[0];
        #pragma unroll
        for (int nt = 0; nt < 4; ++nt) {
            const int c = n0 + nt * 16 + ln;
            const float bias = bo[c];
            #pragma unroll
            for (int mt = 0; mt < 4; ++mt)
                #pragma unroll
                for (int r = 0; r < 4; ++r) {
                    const size_t idx = (size_t)(b * NN + q0 + mt * 16 + lq * 4 + r) * CC + c;
                    out[idx] = gm * (acc[mt][nt][r] + bias) + x[idx];
                }
        }
    }
}

// ---------------------------------------------------------------------------
extern "C" void kernel_launch(void* const* d_in, const int* in_sizes, int n_in,
                              void* d_out, int out_size, void* d_ws, size_t ws_size,
                              hipStream_t stream)
{
    (void)in_sizes; (void)n_in; (void)out_size; (void)ws_size;

    const float* x     = (const float*)d_in[0];
    const float* Wf    = (const float*)d_in[1];
    const float* bf    = (const float*)d_in[2];
    const float* Wg    = (const float*)d_in[3];
    const float* bg    = (const float*)d_in[4];
    const float* Wh    = (const float*)d_in[5];
    const float* bh    = (const float*)d_in[6];
    const float* Wo    = (const float*)d_in[7];
    const float* bo    = (const float*)d_in[8];
    const float* gamma = (const float*)d_in[9];
    float* out = (float*)d_out;

    // ws: f(2MB) | g(2MB) | hhT(16MB) | WThi | WTlo (~0.6MB)
    _Float16* fbuf = (_Float16*)d_ws;
    _Float16* gbuf = fbuf + (size_t)BB * NN * CKK;
    _Float16* hhT  = gbuf + (size_t)BB * NN * CKK;
    unsigned short* WThi = (unsigned short*)(hhT + (size_t)BB * CC * NN);
    unsigned short* WTlo = WThi + (size_t)576 * 256;

    prep_kernel<<<576, 256, 0, stream>>>(Wf, Wg, Wh, Wo, WThi, WTlo);
    fgh_kernel<<<BB * NN / 64, 256, 0, stream>>>(x, WThi, WTlo, bf, bg, bh,
                                                 fbuf, gbuf, hhT);
    attn_kernel<<<BB * NN / 64, 256, 0, stream>>>(fbuf, gbuf, hhT, WThi, WTlo,
                                                  bo, gamma, x, out);
}

// Round 12
// 282.214 us; speedup vs baseline: 1.0087x; 1.0087x over previous
//
#include <hip/hip_runtime.h>
#include <hip/hip_fp16.h>
#include <hip/hip_bf16.h>

constexpr int BB  = 8;
constexpr int NN  = 4096;
constexpr int CC  = 256;
constexpr int CKK = 32;

typedef __attribute__((ext_vector_type(8))) short    short8;  // 8 x bf16 bits
typedef __attribute__((ext_vector_type(8))) _Float16 half8;
typedef __attribute__((ext_vector_type(4))) _Float16 half4;
typedef __attribute__((ext_vector_type(4))) float    f32x4;

__device__ __forceinline__ unsigned short bf16_bits(float v) {
    __hip_bfloat16 h = __float2bfloat16(v);
    return *reinterpret_cast<unsigned short*>(&h);
}
__device__ __forceinline__ float bf16_val(unsigned short u) {
    __hip_bfloat16 h = *reinterpret_cast<__hip_bfloat16*>(&u);
    return __bfloat162float(h);
}
// bare v_exp_f32: identical to ocml exp2f for in-range inputs (ours are
// finite, <= 0); guarded so compilation can't break if builtin is absent.
__device__ __forceinline__ float exp2_x(float x) {
#if __has_builtin(__builtin_amdgcn_exp2f)
    return __builtin_amdgcn_exp2f(x);
#else
    return exp2f(x);
#endif
}

// ---------------------------------------------------------------------------
// K0: transpose + bf16 hi/lo split of all weights into WT[576][256]:
// rows 0..255 = Wh cols, 256..287 = Wf, 288..319 = Wg, 320..575 = Wo.
// ---------------------------------------------------------------------------
__global__ __launch_bounds__(256) void prep_kernel(
    const float* __restrict__ Wf, const float* __restrict__ Wg,
    const float* __restrict__ Wh, const float* __restrict__ Wo,
    unsigned short* __restrict__ WThi, unsigned short* __restrict__ WTlo)
{
    const int n = blockIdx.x;
    const int k = threadIdx.x;
    float v;
    if      (n < 256) v = Wh[k * 256 + n];
    else if (n < 288) v = Wf[k * 32 + (n - 256)];
    else if (n < 320) v = Wg[k * 32 + (n - 288)];
    else              v = Wo[k * 256 + (n - 320)];
    const unsigned short hi = bf16_bits(v);
    WThi[n * 256 + k] = hi;
    WTlo[n * 256 + k] = bf16_bits(v - bf16_val(hi));
}

// ---------------------------------------------------------------------------
// K1: projections (r10/r11 state: LDS-staged A, coalesced hhT stores).
// ---------------------------------------------------------------------------
__global__ __launch_bounds__(256) void fgh_kernel(
    const float* __restrict__ x,
    const unsigned short* __restrict__ WThi, const unsigned short* __restrict__ WTlo,
    const float* __restrict__ bf, const float* __restrict__ bg,
    const float* __restrict__ bh,
    _Float16* __restrict__ fbuf, _Float16* __restrict__ gbuf,
    _Float16* __restrict__ hhT)
{
    __shared__ __align__(16) float XT[2][64 * 36];   // 2 x 9.2 KB dbuf

    const int tid = threadIdx.x, w = tid >> 6, lane = tid & 63;
    const int ln = lane & 15, lq = lane >> 4;
    const int b  = blockIdx.x & 7;               // batch == XCD
    const int q0 = (blockIdx.x >> 3) * 64;
    const size_t px0 = (size_t)b * NN + q0;      // block's 64 pixels
    const int n0 = w * 80;                       // wave's 80 output columns

    const int p  = tid >> 2;
    const int jq = tid & 3;
    const float* xrow = &x[(px0 + p) * CC + jq * 8];

    f32x4 acc[4][5];   // [mt][nt]
    #pragma unroll
    for (int i = 0; i < 4; ++i)
        #pragma unroll
        for (int j = 0; j < 5; ++j) acc[i][j] = {0.f, 0.f, 0.f, 0.f};

    short8 Ahi[4], Alo[4];
    float4 ra0 = *(const float4*)&xrow[0];
    float4 ra1 = *(const float4*)&xrow[4];

    int cur = 0;
    #pragma unroll 1
    for (int kc = 0; kc < 8; ++kc) {
        const int k0 = kc * 32;
        float* dst = &XT[cur][p * 36 + jq * 8];
        *(float4*)&dst[0] = ra0;
        *(float4*)&dst[4] = ra1;
        __syncthreads();
        if (kc < 7) {
            ra0 = *(const float4*)&xrow[(kc + 1) * 32];
            ra1 = *(const float4*)&xrow[(kc + 1) * 32 + 4];
        }
        #pragma unroll
        for (int mt = 0; mt < 4; ++mt) {
            float av[8];
            const float* sp = &XT[cur][(mt * 16 + ln) * 36 + lq * 8];
            *(float4*)&av[0] = *(const float4*)&sp[0];
            *(float4*)&av[4] = *(const float4*)&sp[4];
            #pragma unroll
            for (int j = 0; j < 8; ++j) {
                const unsigned short h = bf16_bits(av[j]);
                Ahi[mt][j] = (short)h;
                Alo[mt][j] = (short)bf16_bits(av[j] - bf16_val(h));
            }
        }
        #pragma unroll
        for (int nt = 0; nt < 5; ++nt) {
            const size_t boff = (size_t)(n0 + nt * 16 + ln) * 256 + k0 + lq * 8;
            const short8 Bhi = *(const short8*)&WThi[boff];
            const short8 Blo = *(const short8*)&WTlo[boff];
            #pragma unroll
            for (int mt = 0; mt < 4; ++mt) {
                acc[mt][nt] = __builtin_amdgcn_mfma_f32_16x16x32_bf16(Ahi[mt], Bhi, acc[mt][nt], 0, 0, 0);
                acc[mt][nt] = __builtin_amdgcn_mfma_f32_16x16x32_bf16(Ahi[mt], Blo, acc[mt][nt], 0, 0, 0);
                acc[mt][nt] = __builtin_amdgcn_mfma_f32_16x16x32_bf16(Alo[mt], Bhi, acc[mt][nt], 0, 0, 0);
            }
        }
        cur ^= 1;
    }

    // ---- stores (r11: hhT via per-wave LDS transpose bounce) ----
    _Float16* st = (_Float16*)&XT[0][0] + w * 1088;
    const int rr = lane >> 3, k8 = lane & 7;

    #pragma unroll
    for (int nt = 0; nt < 5; ++nt) {
        const int cbase = n0 + nt * 16;
        const int c = cbase + ln;
        if (cbase < 256) {
            const float bias = bh[c];
            #pragma unroll
            for (int mt = 0; mt < 4; ++mt) {
                half4 hv;
                #pragma unroll
                for (int r = 0; r < 4; ++r) hv[r] = (_Float16)(acc[mt][nt][r] + bias);
                *(half4*)&st[ln * 68 + mt * 16 + lq * 4] = hv;
            }
            #pragma unroll
            for (int i = 0; i < 2; ++i) {
                const half8 row = *(const half8*)&st[(i * 8 + rr) * 68 + k8 * 8];
                *(half8*)&hhT[((size_t)(b * CC + cbase + i * 8 + rr)) * NN + q0 + k8 * 8] = row;
            }
        } else {
            const bool isf = (c < 288);
            const int d = isf ? (c - 256) : (c - 288);
            const float bias = isf ? bf[d] : bg[d];
            _Float16* dst2 = isf ? fbuf : gbuf;
            #pragma unroll
            for (int mt = 0; mt < 4; ++mt)
                #pragma unroll
                for (int r = 0; r < 4; ++r)
                    dst2[(px0 + mt * 16 + lq * 4 + r) * CKK + d] =
                        (_Float16)(acc[mt][nt][r] + bias);
        }
    }
}

// ---------------------------------------------------------------------------
// K1b: rowmax, EXTRACTED from attn pass-1 and key-split 4-way.
// Inline pass-1 was ~25-35 us of attn's 187: 64 serial (load + 4 MFMA +
// fmax) iters at the same starved 8-waves/CU residency. Standalone with
// grid (512 x 4 key-quarters) = 2048 blocks and VGPR ~50 -> 4x the wave
// parallelism, latency actually hidden. fmax is associative/commutative
// and max is a selection -> regrouping (per-kp chains, then waves, then
// kp in attn) yields the EXACT same mk bits as the old single chain.
// Same per-wave key-slice (j0 + w*16), same MFMA, same merge order shape.
// ---------------------------------------------------------------------------
__global__ __launch_bounds__(256) void rowmax_kernel(
    const _Float16* __restrict__ fbuf, const _Float16* __restrict__ gbuf,
    float* __restrict__ mxpart)
{
    __shared__ float mxbuf[4][64];

    const int tid = threadIdx.x, w = tid >> 6, lane = tid & 63;
    const int ln = lane & 15, lq = lane >> 4;
    const int b  = blockIdx.x & 7;
    const int q0 = (blockIdx.x >> 3) * 64;
    const int kp = blockIdx.y;                   // key quarter: 1024 keys

    const f32x4 zero = {0.f, 0.f, 0.f, 0.f};

    half8 Bg[4];
    #pragma unroll
    for (int qt = 0; qt < 4; ++qt)
        Bg[qt] = *(const half8*)&gbuf[(size_t)(b * NN + q0 + qt * 16 + ln) * CKK + lq * 8];

    const _Float16* fb = &fbuf[(size_t)(b * NN + kp * 1024 + w * 16 + ln) * CKK + lq * 8];

    float mx[4];
    #pragma unroll
    for (int qt = 0; qt < 4; ++qt) mx[qt] = -1e30f;
    half8 Afc = *(const half8*)fb;
    #pragma unroll 1
    for (int j0 = 0; j0 < 1024; j0 += 64) {
        const int jn = (j0 + 64 < 1024) ? j0 + 64 : j0;
        const half8 Afn = *(const half8*)&fb[(size_t)jn * CKK];
        #pragma unroll
        for (int qt = 0; qt < 4; ++qt) {
            const f32x4 s = __builtin_amdgcn_mfma_f32_16x16x32_f16(Afc, Bg[qt], zero, 0, 0, 0);
            mx[qt] = fmaxf(mx[qt], fmaxf(fmaxf(s[0], s[1]), fmaxf(s[2], s[3])));
        }
        Afc = Afn;
    }
    #pragma unroll
    for (int qt = 0; qt < 4; ++qt) {
        mx[qt] = fmaxf(mx[qt], __shfl_xor(mx[qt], 16));
        mx[qt] = fmaxf(mx[qt], __shfl_xor(mx[qt], 32));
    }
    if (lane < 16) {
        #pragma unroll
        for (int qt = 0; qt < 4; ++qt) mxbuf[w][qt * 16 + ln] = mx[qt];
    }
    __syncthreads();
    if (tid < 64) {
        const float m = fmaxf(fmaxf(mxbuf[0][tid], mxbuf[1][tid]),
                              fmaxf(mxbuf[2][tid], mxbuf[3][tid]));
        mxpart[(size_t)kp * (BB * NN) + (size_t)b * NN + q0 + tid] = m;
    }
}

// ---------------------------------------------------------------------------
// K2: MFMA flash attention + FUSED output GEMM. r11 structure, minus
// pass-1 (now rowmax_kernel; mk = LOG2E * fmax over the 4 key-quarter
// partials -- exact same value), plus bare-v_exp phaseA.
// ---------------------------------------------------------------------------
__global__ __launch_bounds__(256, 2) void attn_kernel(
    const _Float16* __restrict__ fbuf, const _Float16* __restrict__ gbuf,
    const _Float16* __restrict__ hhT, const float* __restrict__ mxpart,
    const unsigned short* __restrict__ WThi, const unsigned short* __restrict__ WTlo,
    const float* __restrict__ bo, const float* __restrict__ gamma,
    const float* __restrict__ x, float* __restrict__ out)
{
    // OF (epilogue o-staging, f32 [64][268]) aliases P (main-loop dbuf).
    __shared__ __align__(16) float OF[64 * 268];          // 68.6 KB
    _Float16* P0 = (_Float16*)OF;                          // [64*72] fp16
    _Float16* P1 = P0 + 64 * 72;
    __shared__ float rsbuf[4][64];

    const int tid = threadIdx.x, w = tid >> 6, lane = tid & 63;
    const int ln = lane & 15, lq = lane >> 4;
    const int b  = blockIdx.x & 7;               // batch == XCD
    const int q0 = (blockIdx.x >> 3) * 64;
    const int cb = w * 64;                       // this wave's channel base

    const f32x4 zero = {0.f, 0.f, 0.f, 0.f};
    constexpr float LOG2E = 1.4426950408889634f;

    // persistent g B-frags: B[k=d][n=q]
    half8 Bg[4];
    #pragma unroll
    for (int qt = 0; qt < 4; ++qt)
        Bg[qt] = *(const half8*)&gbuf[(size_t)(b * NN + q0 + qt * 16 + ln) * CKK + lq * 8];

    // base pointers (advance by constants inside loops)
    const _Float16* fb = &fbuf[(size_t)(b * NN + w * 16 + ln) * CKK + lq * 8];
    const _Float16* hb = &hhT[((size_t)(b * CC + cb + ln)) * NN + lq * 8];

    // ---- mk from precomputed key-quarter partial maxes (exact) ----
    float mk[4];
    #pragma unroll
    for (int qt = 0; qt < 4; ++qt) {
        const float* mp = &mxpart[(size_t)b * NN + q0 + qt * 16 + ln];
        const float m = fmaxf(fmaxf(mp[0], mp[BB * NN]),
                              fmaxf(mp[2 * (BB * NN)], mp[3 * (BB * NN)]));
        mk[qt] = LOG2E * m;
    }

    // ---- main loop ----
    f32x4 O[4][4];     // [qt][ct]
    #pragma unroll
    for (int qt = 0; qt < 4; ++qt)
        #pragma unroll
        for (int ct = 0; ct < 4; ++ct) O[qt][ct] = zero;
    float psum[4] = {0.f, 0.f, 0.f, 0.f};

    // phase A: S^T -> exp -> P (LDS)
    auto phaseA = [&](const half8& Af, _Float16* Pb) {
        #pragma unroll
        for (int qt = 0; qt < 4; ++qt) {
            const f32x4 s = __builtin_amdgcn_mfma_f32_16x16x32_f16(Af, Bg[qt], zero, 0, 0, 0);
            half4 ph;
            float ps = 0.f;
            #pragma unroll
            for (int r = 0; r < 4; ++r) {
                const float p = exp2_x(fmaf(s[r], LOG2E, -mk[qt]));
                ps += p;
                ph[r] = (_Float16)p;
            }
            psum[qt] += ps;
            // P[q = qt*16+ln][key = w*16 + lq*4 + r]  (A-layout, pad 72)
            *(half4*)&Pb[(qt * 16 + ln) * 72 + w * 16 + lq * 4] = ph;
        }
    };

    // issue 8 global b128 loads of hhT B-frags for key block j0
    auto loadBh = [&](half8 (&Bh)[4][2], int j0) {
        #pragma unroll
        for (int ct = 0; ct < 4; ++ct)
            #pragma unroll
            for (int kh = 0; kh < 2; ++kh)
                Bh[ct][kh] = *(const half8*)&hb[(size_t)ct * 16 * NN + j0 + kh * 32];
    };

    // phase B: PV for this wave's 64 channels, K=64 via 2 K32 halves
    auto phaseB = [&](const half8 (&Bh)[4][2], const _Float16* Pb) {
        __builtin_amdgcn_s_setprio(1);
        #pragma unroll
        for (int qt = 0; qt < 4; ++qt) {
            const half8 Ap0 = *(const half8*)&Pb[(qt * 16 + ln) * 72 + lq * 8];
            const half8 Ap1 = *(const half8*)&Pb[(qt * 16 + ln) * 72 + 32 + lq * 8];
            #pragma unroll
            for (int ct = 0; ct < 4; ++ct) {
                O[qt][ct] = __builtin_amdgcn_mfma_f32_16x16x32_f16(Ap0, Bh[ct][0], O[qt][ct], 0, 0, 0);
                O[qt][ct] = __builtin_amdgcn_mfma_f32_16x16x32_f16(Ap1, Bh[ct][1], O[qt][ct], 0, 0, 0);
            }
        }
        __builtin_amdgcn_s_setprio(0);
    };

    // prologue: current-iter buffers
    half8 Bh0[4][2], Bh1[4][2];
    half8 Af0, Af1;
    loadBh(Bh0, 0);
    Af0 = *(const half8*)fb;

    #pragma unroll 1
    for (int j0 = 0; j0 < NN; j0 += 128) {
        // --- even 64-key block: uses Bh0/Af0, prefetches Bh1/Af1 ---
        phaseA(Af0, P0);
        __syncthreads();                         // drains Bh0 (issued 1 iter ago)
        loadBh(Bh1, j0 + 64);                    // post-barrier issue: lands during
        Af1 = *(const half8*)&fb[(size_t)(j0 + 64) * CKK];  // phaseB + next phaseA
        phaseB(Bh0, P0);
        // --- odd 64-key block: uses Bh1/Af1, prefetches Bh0/Af0 ---
        phaseA(Af1, P1);
        __syncthreads();
        if (j0 + 128 < NN) {
            loadBh(Bh0, j0 + 128);
            Af0 = *(const half8*)&fb[(size_t)(j0 + 128) * CKK];
        }
        phaseB(Bh1, P1);
    }

    // ---- rowsum merge across waves ----
    #pragma unroll
    for (int qt = 0; qt < 4; ++qt) {
        psum[qt] += __shfl_xor(psum[qt], 16);
        psum[qt] += __shfl_xor(psum[qt], 32);
    }
    if (lane < 16) {
        #pragma unroll
        for (int qt = 0; qt < 4; ++qt) rsbuf[w][qt * 16 + ln] = psum[qt];
    }
    __syncthreads();   // also: all phaseB P-reads done -> P (alias OF) is dead

    // ---- stage normalized o into LDS OF[64][268] ----
    #pragma unroll
    for (int qt = 0; qt < 4; ++qt)
        #pragma unroll
        for (int r = 0; r < 4; ++r) {
            const int q = qt * 16 + lq * 4 + r;
            const float rinv = 1.0f / (rsbuf[0][q] + rsbuf[1][q] + rsbuf[2][q] + rsbuf[3][q]);
            #pragma unroll
            for (int ct = 0; ct < 4; ++ct)
                OF[q * 268 + cb + ct * 16 + ln] = O[qt][ct][r] * rinv;
        }
    __syncthreads();

    // ---- fused out-GEMM: out[64 q][256 c] = gamma*(o @ Wo + bo) + x ----
    {
        const int n0 = w * 64;
        f32x4 acc[4][4];
        #pragma unroll
        for (int i = 0; i < 4; ++i)
            #pragma unroll
            for (int j = 0; j < 4; ++j) acc[i][j] = {0.f, 0.f, 0.f, 0.f};

        short8 Ahi[4], Alo[4];
        #pragma unroll 1
        for (int kc = 0; kc < 8; ++kc) {
            const int k0 = kc * 32;
            #pragma unroll
            for (int mt = 0; mt < 4; ++mt) {
                float av[8];
                *(f32x4*)&av[0] = *(const f32x4*)&OF[(mt * 16 + ln) * 268 + k0 + lq * 8];
                *(f32x4*)&av[4] = *(const f32x4*)&OF[(mt * 16 + ln) * 268 + k0 + lq * 8 + 4];
                #pragma unroll
                for (int j = 0; j < 8; ++j) {
                    const unsigned short h = bf16_bits(av[j]);
                    Ahi[mt][j] = (short)h;
                    Alo[mt][j] = (short)bf16_bits(av[j] - bf16_val(h));
                }
            }
            #pragma unroll
            for (int nt = 0; nt < 4; ++nt) {
                const size_t boff = (size_t)(320 + n0 + nt * 16 + ln) * 256 + k0 + lq * 8;
                const short8 Bhi = *(const short8*)&WThi[boff];
                const short8 Blo = *(const short8*)&WTlo[boff];
                #pragma unroll
                for (int mt = 0; mt < 4; ++mt) {
                    acc[mt][nt] = __builtin_amdgcn_mfma_f32_16x16x32_bf16(Ahi[mt], Bhi, acc[mt][nt], 0, 0, 0);
                    acc[mt][nt] = __builtin_amdgcn_mfma_f32_16x16x32_bf16(Ahi[mt], Blo, acc[mt][nt], 0, 0, 0);
                    acc[mt][nt] = __builtin_amdgcn_mfma_f32_16x16x32_bf16(Alo[mt], Bhi, acc[mt][nt], 0, 0, 0);
                }
            }
        }

        const float gm = gamma[0];
        #pragma unroll
        for (int nt = 0; nt < 4; ++nt) {
            const int c = n0 + nt * 16 + ln;
            const float bias = bo[c];
            #pragma unroll
            for (int mt = 0; mt < 4; ++mt)
                #pragma unroll
                for (int r = 0; r < 4; ++r) {
                    const size_t idx = (size_t)(b * NN + q0 + mt * 16 + lq * 4 + r) * CC + c;
                    out[idx] = gm * (acc[mt][nt][r] + bias) + x[idx];
                }
        }
    }
}

// ---------------------------------------------------------------------------
extern "C" void kernel_launch(void* const* d_in, const int* in_sizes, int n_in,
                              void* d_out, int out_size, void* d_ws, size_t ws_size,
                              hipStream_t stream)
{
    (void)in_sizes; (void)n_in; (void)out_size; (void)ws_size;

    const float* x     = (const float*)d_in[0];
    const float* Wf    = (const float*)d_in[1];
    const float* bf    = (const float*)d_in[2];
    const float* Wg    = (const float*)d_in[3];
    const float* bg    = (const float*)d_in[4];
    const float* Wh    = (const float*)d_in[5];
    const float* bh    = (const float*)d_in[6];
    const float* Wo    = (const float*)d_in[7];
    const float* bo    = (const float*)d_in[8];
    const float* gamma = (const float*)d_in[9];
    float* out = (float*)d_out;

    // ws: f(2MB) | g(2MB) | hhT(16MB) | WThi | WTlo (~0.6MB) | mxpart(512KB)
    _Float16* fbuf = (_Float16*)d_ws;
    _Float16* gbuf = fbuf + (size_t)BB * NN * CKK;
    _Float16* hhT  = gbuf + (size_t)BB * NN * CKK;
    unsigned short* WThi = (unsigned short*)(hhT + (size_t)BB * CC * NN);
    unsigned short* WTlo = WThi + (size_t)576 * 256;
    float* mxpart = (float*)(WTlo + (size_t)576 * 256);

    prep_kernel<<<576, 256, 0, stream>>>(Wf, Wg, Wh, Wo, WThi, WTlo);
    fgh_kernel<<<BB * NN / 64, 256, 0, stream>>>(x, WThi, WTlo, bf, bg, bh,
                                                 fbuf, gbuf, hhT);
    rowmax_kernel<<<dim3(BB * NN / 64, 4), 256, 0, stream>>>(fbuf, gbuf, mxpart);
    attn_kernel<<<BB * NN / 64, 256, 0, stream>>>(fbuf, gbuf, hhT, mxpart, WThi, WTlo,
                                                  bo, gamma, x, out);
}